// Round 4
// baseline (1076.442 us; speedup 1.0000x reference)
//
#include <hip/hip_runtime.h>
#include <math.h>

#define NN 40000
#define EE 640000
#define DD 128
#define EDD 16
#define LL 3

__device__ __constant__ float kBnInv = 0.9999950000374997f; // 1/sqrt(1+1e-5)

// ---------------------------------------------------------------------------
// h = x @ node_W + node_b   ([40000,128] @ [128,128])
__global__ __launch_bounds__(256) void node_enc_kernel(
    const float* __restrict__ x, const float* __restrict__ W,
    const float* __restrict__ b, float* __restrict__ h)
{
    __shared__ float xs[32][DD];
    const int t = threadIdx.x;
    const long rowbase = (long)blockIdx.x * 32;

    const float4* x4 = (const float4*)(x + rowbase * DD);
    float4* xs4 = (float4*)&xs[0][0];
#pragma unroll
    for (int i = 0; i < 4; i++) xs4[t + i * 256] = x4[t + i * 256];
    __syncthreads();

    const int c  = (t & 31) * 4;
    const int r0 = (t >> 5) * 4;

    float acc[4][4] = {};
    for (int k4 = 0; k4 < DD; k4 += 4) {
        float4 xr[4];
#pragma unroll
        for (int i = 0; i < 4; i++) xr[i] = *(const float4*)&xs[r0 + i][k4];
#pragma unroll
        for (int kk = 0; kk < 4; kk++) {
            const float4 w = *(const float4*)(W + (k4 + kk) * DD + c);
#pragma unroll
            for (int i = 0; i < 4; i++) {
                const float xv = ((const float*)&xr[i])[kk];
                acc[i][0] = fmaf(xv, w.x, acc[i][0]);
                acc[i][1] = fmaf(xv, w.y, acc[i][1]);
                acc[i][2] = fmaf(xv, w.z, acc[i][2]);
                acc[i][3] = fmaf(xv, w.w, acc[i][3]);
            }
        }
    }
    const float4 bv = *(const float4*)(b + c);
#pragma unroll
    for (int i = 0; i < 4; i++) {
        float4 ov = { acc[i][0] + bv.x, acc[i][1] + bv.y,
                      acc[i][2] + bv.z, acc[i][3] + bv.w };
        *(float4*)(h + (rowbase + r0 + i) * DD + c) = ov;
    }
}

// ---------------------------------------------------------------------------
// CSR build
__global__ __launch_bounds__(256) void hist_kernel(
    const int* __restrict__ edge_index, int* __restrict__ counts)
{
    const int i = blockIdx.x * 256 + threadIdx.x;
    atomicAdd(&counts[edge_index[EE + i]], 1);
}

__global__ __launch_bounds__(256) void scan1_kernel(
    const int* __restrict__ counts, int* __restrict__ scanned,
    int* __restrict__ partials)
{
    __shared__ int sdata[256];
    const int t = threadIdx.x;
    const int base = blockIdx.x * 1024 + t * 4;
    int v[4]; int sum = 0;
#pragma unroll
    for (int i = 0; i < 4; i++) {
        const int idx = base + i;
        v[i] = (idx < NN) ? counts[idx] : 0;
        sum += v[i];
    }
    sdata[t] = sum;
    __syncthreads();
    for (int off = 1; off < 256; off <<= 1) {
        int x = (t >= off) ? sdata[t - off] : 0;
        __syncthreads();
        sdata[t] += x;
        __syncthreads();
    }
    int run = sdata[t] - sum;
#pragma unroll
    for (int i = 0; i < 4; i++) {
        const int idx = base + i;
        if (idx < NN) scanned[idx] = run;
        run += v[i];
    }
    if (t == 255) partials[blockIdx.x] = sdata[255];
}

__global__ void scan2_kernel(int* __restrict__ partials)
{
    if (threadIdx.x == 0) {
        int run = 0;
        for (int i = 0; i < 40; i++) { int v = partials[i]; partials[i] = run; run += v; }
    }
}

__global__ __launch_bounds__(256) void scan3_kernel(
    const int* __restrict__ scanned, const int* __restrict__ partials,
    int* __restrict__ offsets, int* __restrict__ cursor)
{
    const int idx = blockIdx.x * 256 + threadIdx.x;
    if (idx < NN) {
        const int off = scanned[idx] + partials[idx >> 10];
        offsets[idx] = off;
        cursor[idx]  = off;
    }
}

__global__ __launch_bounds__(256) void scatter_kernel(
    const int* __restrict__ edge_index, int* __restrict__ cursor,
    int* __restrict__ perm, int* __restrict__ src_p, int* __restrict__ dst_p)
{
    const int i = blockIdx.x * 256 + threadIdx.x;
    const int src = edge_index[i];
    const int dst = edge_index[EE + i];
    const int pos = atomicAdd(&cursor[dst], 1);
    perm[pos] = i;
    src_p[pos] = src;
    dst_p[pos] = dst;
}

__global__ __launch_bounds__(256) void ea_perm_kernel(
    const float* __restrict__ edge_attr, const int* __restrict__ perm,
    float* __restrict__ ea_p)
{
    const int pos = blockIdx.x * 256 + threadIdx.x;
    const int e = perm[pos];
    const float4* sp = (const float4*)(edge_attr + (long)e * EDD);
    float4* dp = (float4*)(ea_p + (long)pos * EDD);
    dp[0] = sp[0]; dp[1] = sp[1]; dp[2] = sp[2]; dp[3] = sp[3];
}

// ---------------------------------------------------------------------------
// per-node attention partials
__global__ __launch_bounds__(256) void attn_pre_kernel(
    const float* __restrict__ h, const float* __restrict__ aW,
    float* __restrict__ pi, float* __restrict__ pj)
{
    const int wid  = threadIdx.x >> 6;
    const int lane = threadIdx.x & 63;
    const int n = blockIdx.x * 4 + wid;
    const int c0 = lane, c1 = lane + 64;
    const float h0 = h[(long)n * DD + c0], h1 = h[(long)n * DD + c1];
    float a = h0 * aW[c0]      + h1 * aW[c1];
    float b = h0 * aW[DD + c0] + h1 * aW[DD + c1];
#pragma unroll
    for (int off = 32; off > 0; off >>= 1) {
        a += __shfl_xor(a, off, 64);
        b += __shfl_xor(b, off, 64);
    }
    if (lane == 0) { pi[n] = a; pj[n] = b; }
}

// per-edge attention coefficient in CSR order
__global__ __launch_bounds__(256) void attn_edge_kernel(
    const float* __restrict__ pi, const float* __restrict__ pj,
    const int* __restrict__ src_p, const int* __restrict__ dst_p,
    const float* __restrict__ ab_p, float* __restrict__ a_p)
{
    const int idx = blockIdx.x * 256 + threadIdx.x;
    const float s = pi[dst_p[idx]] + pj[src_p[idx]] + ab_p[0];
    a_p[idx] = 1.0f / (1.0f + expf(-s));
}

// ---------------------------------------------------------------------------
// Dst-centric aggregation: 2 waves per node (64 cols each), software-pipelined
// (meta 2 ahead, h-gather 1 ahead).
#define EV16(ev, e0, e1, e2, e3)                         \
    ev = fmaf((e0).x, ew[0],  ev); ev = fmaf((e0).y, ew[1],  ev);  \
    ev = fmaf((e0).z, ew[2],  ev); ev = fmaf((e0).w, ew[3],  ev);  \
    ev = fmaf((e1).x, ew[4],  ev); ev = fmaf((e1).y, ew[5],  ev);  \
    ev = fmaf((e1).z, ew[6],  ev); ev = fmaf((e1).w, ew[7],  ev);  \
    ev = fmaf((e2).x, ew[8],  ev); ev = fmaf((e2).y, ew[9],  ev);  \
    ev = fmaf((e2).z, ew[10], ev); ev = fmaf((e2).w, ew[11], ev);  \
    ev = fmaf((e3).x, ew[12], ev); ev = fmaf((e3).y, ew[13], ev);  \
    ev = fmaf((e3).z, ew[14], ev); ev = fmaf((e3).w, ew[15], ev)

__global__ __launch_bounds__(256) void edge_agg_kernel(
    const float* __restrict__ h, const float* __restrict__ ea_p,
    const float* __restrict__ a_p, const int* __restrict__ src_p,
    const int* __restrict__ offsets, const int* __restrict__ counts,
    const float* __restrict__ eW, const float* __restrict__ eb,
    const float* __restrict__ eps_p, float* __restrict__ z)
{
    const int wid  = threadIdx.x >> 6;
    const int lane = threadIdx.x & 63;
    const int w    = blockIdx.x * 4 + wid;   // grid = NN/2 blocks
    const int n    = w >> 1;
    const int c    = lane + ((w & 1) << 6);  // which 64-col half

    float ew[EDD];
#pragma unroll
    for (int q = 0; q < EDD; q++) ew[q] = eW[q * DD + c];
    const float ebc = eb[c];
    const float ep  = 1.0f + eps_p[0];
    const float xi  = h[(long)n * DD + c];

    float acc = 0.0f;
    const long s  = offsets[n];
    const int cnt = counts[n];

    if (cnt > 0) {
        const long last = s + cnt - 1;

        // prologue: meta(0) -> A
        int   srcA = src_p[s];
        float aA   = a_p[s];
        const float4* eap0 = (const float4*)(ea_p + s * EDD);
        float4 eA0 = eap0[0], eA1 = eap0[1], eA2 = eap0[2], eA3 = eap0[3];

        float xjA = h[(long)srcA * DD + c];   // hload(0)

        float evA = ebc;
        EV16(evA, eA0, eA1, eA2, eA3);        // ev(0)

        // meta(1) -> B
        const long p1 = (cnt > 1) ? (s + 1) : last;
        int   srcB = src_p[p1];
        float aB   = a_p[p1];
        const float4* eap1 = (const float4*)(ea_p + p1 * EDD);
        float4 eB0 = eap1[0], eB1 = eap1[1], eB2 = eap1[2], eB3 = eap1[3];

#pragma unroll 2
        for (int k = 0; k < cnt; k++) {
            // 1: hload(k+1) — src already resident
            const float xjB = h[(long)srcB * DD + c];
            // 2: meta(k+2) -> C (clamped; harmless duplicate at tail)
            const long p2 = (k + 2 < cnt) ? (s + k + 2) : last;
            const int   srcC = src_p[p2];
            const float aC   = a_p[p2];
            const float4* eap2 = (const float4*)(ea_p + p2 * EDD);
            const float4 eC0 = eap2[0], eC1 = eap2[1],
                         eC2 = eap2[2], eC3 = eap2[3];
            // 3: ev(k+1) from B meta (no wait — loaded last iteration)
            float evB = ebc;
            EV16(evB, eB0, eB1, eB2, eB3);
            // 4: consume edge k
            acc += fmaxf(fmaf(xjA, aA, evA), 0.0f);
            // rotate (renamed away by unroll)
            xjA = xjB; evA = evB; aA = aB;
            srcB = srcC; aB = aC;
            eB0 = eC0; eB1 = eC1; eB2 = eC2; eB3 = eC3;
        }
    }

    z[(long)n * DD + c] = fmaf(ep, xi, acc);
}

// ---------------------------------------------------------------------------
// Fused GIN MLP, 32 rows/block.
__global__ __launch_bounds__(256) void mlp_kernel(
    const float* __restrict__ zin,
    const float* __restrict__ W1, const float* __restrict__ b1,
    const float* __restrict__ g1, const float* __restrict__ bb1,
    const float* __restrict__ W2, const float* __restrict__ b2,
    const float* __restrict__ g2, const float* __restrict__ bb2,
    float* __restrict__ out, const int do_relu)
{
    __shared__ float zs[32][DD];
    __shared__ float us[32][2 * DD];
    const int t = threadIdx.x;
    const long rowbase = (long)blockIdx.x * 32;

    const float4* z4in = (const float4*)(zin + rowbase * DD);
    float4* z4 = (float4*)&zs[0][0];
#pragma unroll
    for (int i = 0; i < 4; i++) z4[t + i * 256] = z4in[t + i * 256];
    __syncthreads();

    {
        const int c  = (t & 63) * 4;
        const int r0 = (t >> 6) * 8;
        float acc[8][4] = {};
        for (int k4 = 0; k4 < DD; k4 += 4) {
            float4 zr[8];
#pragma unroll
            for (int i = 0; i < 8; i++) zr[i] = *(const float4*)&zs[r0 + i][k4];
#pragma unroll
            for (int kk = 0; kk < 4; kk++) {
                const float4 w = *(const float4*)(W1 + (k4 + kk) * 2 * DD + c);
#pragma unroll
                for (int i = 0; i < 8; i++) {
                    const float zv = ((const float*)&zr[i])[kk];
                    acc[i][0] = fmaf(zv, w.x, acc[i][0]);
                    acc[i][1] = fmaf(zv, w.y, acc[i][1]);
                    acc[i][2] = fmaf(zv, w.z, acc[i][2]);
                    acc[i][3] = fmaf(zv, w.w, acc[i][3]);
                }
            }
        }
        const float4 b1v = *(const float4*)(b1 + c);
        const float4 g1v = *(const float4*)(g1 + c);
        const float4 s1v = *(const float4*)(bb1 + c);
#pragma unroll
        for (int i = 0; i < 8; i++) {
            float4 uv;
            uv.x = fmaxf(fmaf(g1v.x * (acc[i][0] + b1v.x), kBnInv, s1v.x), 0.0f);
            uv.y = fmaxf(fmaf(g1v.y * (acc[i][1] + b1v.y), kBnInv, s1v.y), 0.0f);
            uv.z = fmaxf(fmaf(g1v.z * (acc[i][2] + b1v.z), kBnInv, s1v.z), 0.0f);
            uv.w = fmaxf(fmaf(g1v.w * (acc[i][3] + b1v.w), kBnInv, s1v.w), 0.0f);
            *(float4*)&us[r0 + i][c] = uv;
        }
    }
    __syncthreads();

    {
        const int c  = (t & 31) * 4;
        const int r0 = (t >> 5) * 4;
        float acc[4][4] = {};
        for (int k4 = 0; k4 < 2 * DD; k4 += 4) {
            float4 ur[4];
#pragma unroll
            for (int i = 0; i < 4; i++) ur[i] = *(const float4*)&us[r0 + i][k4];
#pragma unroll
            for (int kk = 0; kk < 4; kk++) {
                const float4 w = *(const float4*)(W2 + (k4 + kk) * DD + c);
#pragma unroll
                for (int i = 0; i < 4; i++) {
                    const float uv = ((const float*)&ur[i])[kk];
                    acc[i][0] = fmaf(uv, w.x, acc[i][0]);
                    acc[i][1] = fmaf(uv, w.y, acc[i][1]);
                    acc[i][2] = fmaf(uv, w.z, acc[i][2]);
                    acc[i][3] = fmaf(uv, w.w, acc[i][3]);
                }
            }
        }
        const float4 b2v = *(const float4*)(b2 + c);
        const float4 g2v = *(const float4*)(g2 + c);
        const float4 s2v = *(const float4*)(bb2 + c);
#pragma unroll
        for (int i = 0; i < 4; i++) {
            float4 ov;
            ov.x = fmaf(g2v.x * (acc[i][0] + b2v.x), kBnInv, s2v.x);
            ov.y = fmaf(g2v.y * (acc[i][1] + b2v.y), kBnInv, s2v.y);
            ov.z = fmaf(g2v.z * (acc[i][2] + b2v.z), kBnInv, s2v.z);
            ov.w = fmaf(g2v.w * (acc[i][3] + b2v.w), kBnInv, s2v.w);
            if (do_relu) {
                ov.x = fmaxf(ov.x, 0.0f); ov.y = fmaxf(ov.y, 0.0f);
                ov.z = fmaxf(ov.z, 0.0f); ov.w = fmaxf(ov.w, 0.0f);
            }
            *(float4*)(out + (rowbase + r0 + i) * DD + c) = ov;
        }
    }
}

// ---------------------------------------------------------------------------
extern "C" void kernel_launch(void* const* d_in, const int* in_sizes, int n_in,
                              void* d_out, int out_size, void* d_ws, size_t ws_size,
                              hipStream_t stream)
{
    const float* x         = (const float*)d_in[0];
    const float* edge_attr = (const float*)d_in[1];
    const float* node_W    = (const float*)d_in[2];
    const float* node_b    = (const float*)d_in[3];
    const float* edge_W    = (const float*)d_in[4];
    const float* edge_b    = (const float*)d_in[5];
    const float* attn_W    = (const float*)d_in[6];
    const float* attn_b    = (const float*)d_in[7];
    const float* eps       = (const float*)d_in[8];
    const float* W1        = (const float*)d_in[9];
    const float* b1        = (const float*)d_in[10];
    const float* bn1_g     = (const float*)d_in[11];
    const float* bn1_b     = (const float*)d_in[12];
    const float* W2        = (const float*)d_in[13];
    const float* b2        = (const float*)d_in[14];
    const float* bn_g      = (const float*)d_in[15];
    const float* bn_b      = (const float*)d_in[16];
    const int*   edge_index= (const int*)d_in[17];

    float* h    = (float*)d_ws;                     // [N*D]
    float* z    = h + (size_t)NN * DD;              // [N*D]
    float* pi   = z + (size_t)NN * DD;              // [N]
    float* pj   = pi + NN;                          // [N]
    float* a_p  = pj + NN;                          // [E]
    float* ea_p = a_p + EE;                         // [E*16]
    int* counts  = (int*)(ea_p + (size_t)EE * EDD); // [N]
    int* offsets = counts + NN;                     // [N]
    int* cursor  = offsets + NN;                    // [N]
    int* scanned = cursor + NN;                     // [40960]
    int* partials= scanned + 40960;                 // [64]
    int* perm    = partials + 64;                   // [E]
    int* src_p   = perm + EE;                       // [E]
    int* dst_p   = src_p + EE;                      // [E]
    float* out = (float*)d_out;

    node_enc_kernel<<<NN / 32, 256, 0, stream>>>(x, node_W, node_b, h);

    hipMemsetAsync(counts, 0, NN * sizeof(int), stream);
    hist_kernel<<<EE / 256, 256, 0, stream>>>(edge_index, counts);
    scan1_kernel<<<40, 256, 0, stream>>>(counts, scanned, partials);
    scan2_kernel<<<1, 64, 0, stream>>>(partials);
    scan3_kernel<<<(NN + 255) / 256, 256, 0, stream>>>(scanned, partials, offsets, cursor);
    scatter_kernel<<<EE / 256, 256, 0, stream>>>(edge_index, cursor, perm, src_p, dst_p);
    ea_perm_kernel<<<EE / 256, 256, 0, stream>>>(edge_attr, perm, ea_p);

    for (int l = 0; l < LL; l++) {
        attn_pre_kernel<<<NN / 4, 256, 0, stream>>>(h, attn_W + (size_t)l * 2 * DD, pi, pj);
        attn_edge_kernel<<<EE / 256, 256, 0, stream>>>(pi, pj, src_p, dst_p, attn_b + l, a_p);
        edge_agg_kernel<<<NN / 2, 256, 0, stream>>>(
            h, ea_p, a_p, src_p, offsets, counts,
            edge_W + (size_t)l * EDD * DD, edge_b + (size_t)l * DD, eps + l, z);
        mlp_kernel<<<NN / 32, 256, 0, stream>>>(
            z,
            W1 + (size_t)l * DD * 2 * DD, b1 + (size_t)l * 2 * DD,
            bn1_g + (size_t)l * 2 * DD, bn1_b + (size_t)l * 2 * DD,
            W2 + (size_t)l * 2 * DD * DD, b2 + (size_t)l * DD,
            bn_g + (size_t)l * DD, bn_b + (size_t)l * DD,
            (l == LL - 1) ? out : h, (l < LL - 1) ? 1 : 0);
    }
}

// Round 5
// 855.357 us; speedup vs baseline: 1.2585x; 1.2585x over previous
//
#include <hip/hip_runtime.h>
#include <math.h>

#define NN 40000
#define EE 640000
#define DD 128
#define EDD 16
#define LL 3
#define CH 64   // edges per wave in edge_msg_kernel

__device__ __constant__ float kBnInv = 0.9999950000374997f; // 1/sqrt(1+1e-5)

// ---------------------------------------------------------------------------
// h = x @ node_W + node_b   ([40000,128] @ [128,128])
__global__ __launch_bounds__(256) void node_enc_kernel(
    const float* __restrict__ x, const float* __restrict__ W,
    const float* __restrict__ b, float* __restrict__ h)
{
    __shared__ float xs[32][DD];
    const int t = threadIdx.x;
    const long rowbase = (long)blockIdx.x * 32;

    const float4* x4 = (const float4*)(x + rowbase * DD);
    float4* xs4 = (float4*)&xs[0][0];
#pragma unroll
    for (int i = 0; i < 4; i++) xs4[t + i * 256] = x4[t + i * 256];
    __syncthreads();

    const int c  = (t & 31) * 4;
    const int r0 = (t >> 5) * 4;

    float acc[4][4] = {};
    for (int k4 = 0; k4 < DD; k4 += 4) {
        float4 xr[4];
#pragma unroll
        for (int i = 0; i < 4; i++) xr[i] = *(const float4*)&xs[r0 + i][k4];
#pragma unroll
        for (int kk = 0; kk < 4; kk++) {
            const float4 w = *(const float4*)(W + (k4 + kk) * DD + c);
#pragma unroll
            for (int i = 0; i < 4; i++) {
                const float xv = ((const float*)&xr[i])[kk];
                acc[i][0] = fmaf(xv, w.x, acc[i][0]);
                acc[i][1] = fmaf(xv, w.y, acc[i][1]);
                acc[i][2] = fmaf(xv, w.z, acc[i][2]);
                acc[i][3] = fmaf(xv, w.w, acc[i][3]);
            }
        }
    }
    const float4 bv = *(const float4*)(b + c);
#pragma unroll
    for (int i = 0; i < 4; i++) {
        float4 ov = { acc[i][0] + bv.x, acc[i][1] + bv.y,
                      acc[i][2] + bv.z, acc[i][3] + bv.w };
        *(float4*)(h + (rowbase + r0 + i) * DD + c) = ov;
    }
}

// ---------------------------------------------------------------------------
// CSR build
__global__ __launch_bounds__(256) void hist_kernel(
    const int* __restrict__ edge_index, int* __restrict__ counts)
{
    const int i = blockIdx.x * 256 + threadIdx.x;
    atomicAdd(&counts[edge_index[EE + i]], 1);
}

__global__ __launch_bounds__(256) void scan1_kernel(
    const int* __restrict__ counts, int* __restrict__ scanned,
    int* __restrict__ partials)
{
    __shared__ int sdata[256];
    const int t = threadIdx.x;
    const int base = blockIdx.x * 1024 + t * 4;
    int v[4]; int sum = 0;
#pragma unroll
    for (int i = 0; i < 4; i++) {
        const int idx = base + i;
        v[i] = (idx < NN) ? counts[idx] : 0;
        sum += v[i];
    }
    sdata[t] = sum;
    __syncthreads();
    for (int off = 1; off < 256; off <<= 1) {
        int x = (t >= off) ? sdata[t - off] : 0;
        __syncthreads();
        sdata[t] += x;
        __syncthreads();
    }
    int run = sdata[t] - sum;
#pragma unroll
    for (int i = 0; i < 4; i++) {
        const int idx = base + i;
        if (idx < NN) scanned[idx] = run;
        run += v[i];
    }
    if (t == 255) partials[blockIdx.x] = sdata[255];
}

__global__ void scan2_kernel(int* __restrict__ partials)
{
    if (threadIdx.x == 0) {
        int run = 0;
        for (int i = 0; i < 40; i++) { int v = partials[i]; partials[i] = run; run += v; }
    }
}

__global__ __launch_bounds__(256) void scan3_kernel(
    const int* __restrict__ scanned, const int* __restrict__ partials,
    int* __restrict__ offsets, int* __restrict__ cursor)
{
    const int idx = blockIdx.x * 256 + threadIdx.x;
    if (idx < NN) {
        const int off = scanned[idx] + partials[idx >> 10];
        offsets[idx] = off;
        cursor[idx]  = off;
    }
}

__global__ __launch_bounds__(256) void scatter_kernel(
    const int* __restrict__ edge_index, int* __restrict__ cursor,
    int* __restrict__ perm, int* __restrict__ src_p, int* __restrict__ dst_p)
{
    const int i = blockIdx.x * 256 + threadIdx.x;
    const int src = edge_index[i];
    const int dst = edge_index[EE + i];
    const int pos = atomicAdd(&cursor[dst], 1);
    perm[pos] = i;
    src_p[pos] = src;
    dst_p[pos] = dst;
}

__global__ __launch_bounds__(256) void ea_perm_kernel(
    const float* __restrict__ edge_attr, const int* __restrict__ perm,
    float* __restrict__ ea_p)
{
    const int pos = blockIdx.x * 256 + threadIdx.x;
    const int e = perm[pos];
    const float4* sp = (const float4*)(edge_attr + (long)e * EDD);
    float4* dp = (float4*)(ea_p + (long)pos * EDD);
    dp[0] = sp[0]; dp[1] = sp[1]; dp[2] = sp[2]; dp[3] = sp[3];
}

// ---------------------------------------------------------------------------
// per-node attention partials + z init (z = (1+eps)*h)
__global__ __launch_bounds__(256) void attn_pre_kernel(
    const float* __restrict__ h, const float* __restrict__ aW,
    const float* __restrict__ eps_p,
    float* __restrict__ pi, float* __restrict__ pj, float* __restrict__ z)
{
    const int wid  = threadIdx.x >> 6;
    const int lane = threadIdx.x & 63;
    const int n = blockIdx.x * 4 + wid;
    const int c0 = lane, c1 = lane + 64;
    const float ep = 1.0f + eps_p[0];
    const float h0 = h[(long)n * DD + c0], h1 = h[(long)n * DD + c1];

    z[(long)n * DD + c0] = ep * h0;
    z[(long)n * DD + c1] = ep * h1;

    float a = h0 * aW[c0]      + h1 * aW[c1];
    float b = h0 * aW[DD + c0] + h1 * aW[DD + c1];
#pragma unroll
    for (int off = 32; off > 0; off >>= 1) {
        a += __shfl_xor(a, off, 64);
        b += __shfl_xor(b, off, 64);
    }
    if (lane == 0) { pi[n] = a; pj[n] = b; }
}

// per-edge attention coefficient in CSR order
__global__ __launch_bounds__(256) void attn_edge_kernel(
    const float* __restrict__ pi, const float* __restrict__ pj,
    const int* __restrict__ src_p, const int* __restrict__ dst_p,
    const float* __restrict__ ab_p, float* __restrict__ a_p)
{
    const int idx = blockIdx.x * 256 + threadIdx.x;
    const float s = pi[dst_p[idx]] + pj[src_p[idx]] + ab_p[0];
    a_p[idx] = 1.0f / (1.0f + expf(-s));
}

// ---------------------------------------------------------------------------
// Edge-parallel segmented aggregation. Each wave owns CH consecutive CSR
// edges (perfect load balance, all meta loads are sequential streams).
// Register-accumulate while dst unchanged; atomic flush on segment change.
// z must be pre-initialized to (1+eps)*h.
__global__ __launch_bounds__(256) void edge_msg_kernel(
    const float* __restrict__ h, const float* __restrict__ ea_p,
    const float* __restrict__ a_p,
    const int* __restrict__ src_p, const int* __restrict__ dst_p,
    const float* __restrict__ eW, const float* __restrict__ eb,
    float* __restrict__ z)
{
    const int wid  = threadIdx.x >> 6;
    const int lane = threadIdx.x & 63;
    const long e0  = ((long)blockIdx.x * 4 + wid) * CH;  // grid = EE/(4*CH)
    const int c0 = lane, c1 = lane + 64;

    float ew0[EDD], ew1[EDD];
#pragma unroll
    for (int q = 0; q < EDD; q++) {
        ew0[q] = eW[q * DD + c0];
        ew1[q] = eW[q * DD + c1];
    }
    const float eb0 = eb[c0], eb1 = eb[c1];

    float acc0 = 0.0f, acc1 = 0.0f;
    int cur = dst_p[e0];

#pragma unroll 4
    for (int k = 0; k < CH; k++) {
        const long e = e0 + k;
        const int dst = dst_p[e];
        const int src = src_p[e];
        const float a = a_p[e];

        if (dst != cur) {   // wave-uniform branch
            atomicAdd(&z[(long)cur * DD + c0], acc0);
            atomicAdd(&z[(long)cur * DD + c1], acc1);
            acc0 = 0.0f; acc1 = 0.0f;
            cur = dst;
        }

        const float4* eap = (const float4*)(ea_p + e * EDD);
        const float4 t0 = eap[0], t1 = eap[1], t2 = eap[2], t3 = eap[3];

        float ev0 = eb0, ev1 = eb1;
        ev0 = fmaf(t0.x, ew0[0],  ev0); ev1 = fmaf(t0.x, ew1[0],  ev1);
        ev0 = fmaf(t0.y, ew0[1],  ev0); ev1 = fmaf(t0.y, ew1[1],  ev1);
        ev0 = fmaf(t0.z, ew0[2],  ev0); ev1 = fmaf(t0.z, ew1[2],  ev1);
        ev0 = fmaf(t0.w, ew0[3],  ev0); ev1 = fmaf(t0.w, ew1[3],  ev1);
        ev0 = fmaf(t1.x, ew0[4],  ev0); ev1 = fmaf(t1.x, ew1[4],  ev1);
        ev0 = fmaf(t1.y, ew0[5],  ev0); ev1 = fmaf(t1.y, ew1[5],  ev1);
        ev0 = fmaf(t1.z, ew0[6],  ev0); ev1 = fmaf(t1.z, ew1[6],  ev1);
        ev0 = fmaf(t1.w, ew0[7],  ev0); ev1 = fmaf(t1.w, ew1[7],  ev1);
        ev0 = fmaf(t2.x, ew0[8],  ev0); ev1 = fmaf(t2.x, ew1[8],  ev1);
        ev0 = fmaf(t2.y, ew0[9],  ev0); ev1 = fmaf(t2.y, ew1[9],  ev1);
        ev0 = fmaf(t2.z, ew0[10], ev0); ev1 = fmaf(t2.z, ew1[10], ev1);
        ev0 = fmaf(t2.w, ew0[11], ev0); ev1 = fmaf(t2.w, ew1[11], ev1);
        ev0 = fmaf(t3.x, ew0[12], ev0); ev1 = fmaf(t3.x, ew1[12], ev1);
        ev0 = fmaf(t3.y, ew0[13], ev0); ev1 = fmaf(t3.y, ew1[13], ev1);
        ev0 = fmaf(t3.z, ew0[14], ev0); ev1 = fmaf(t3.z, ew1[14], ev1);
        ev0 = fmaf(t3.w, ew0[15], ev0); ev1 = fmaf(t3.w, ew1[15], ev1);

        const float xj0 = h[(long)src * DD + c0];
        const float xj1 = h[(long)src * DD + c1];

        acc0 += fmaxf(fmaf(xj0, a, ev0), 0.0f);
        acc1 += fmaxf(fmaf(xj1, a, ev1), 0.0f);
    }
    atomicAdd(&z[(long)cur * DD + c0], acc0);
    atomicAdd(&z[(long)cur * DD + c1], acc1);
}

// ---------------------------------------------------------------------------
// Fused GIN MLP, 32 rows/block.
__global__ __launch_bounds__(256) void mlp_kernel(
    const float* __restrict__ zin,
    const float* __restrict__ W1, const float* __restrict__ b1,
    const float* __restrict__ g1, const float* __restrict__ bb1,
    const float* __restrict__ W2, const float* __restrict__ b2,
    const float* __restrict__ g2, const float* __restrict__ bb2,
    float* __restrict__ out, const int do_relu)
{
    __shared__ float zs[32][DD];
    __shared__ float us[32][2 * DD];
    const int t = threadIdx.x;
    const long rowbase = (long)blockIdx.x * 32;

    const float4* z4in = (const float4*)(zin + rowbase * DD);
    float4* z4 = (float4*)&zs[0][0];
#pragma unroll
    for (int i = 0; i < 4; i++) z4[t + i * 256] = z4in[t + i * 256];
    __syncthreads();

    {
        const int c  = (t & 63) * 4;
        const int r0 = (t >> 6) * 8;
        float acc[8][4] = {};
        for (int k4 = 0; k4 < DD; k4 += 4) {
            float4 zr[8];
#pragma unroll
            for (int i = 0; i < 8; i++) zr[i] = *(const float4*)&zs[r0 + i][k4];
#pragma unroll
            for (int kk = 0; kk < 4; kk++) {
                const float4 w = *(const float4*)(W1 + (k4 + kk) * 2 * DD + c);
#pragma unroll
                for (int i = 0; i < 8; i++) {
                    const float zv = ((const float*)&zr[i])[kk];
                    acc[i][0] = fmaf(zv, w.x, acc[i][0]);
                    acc[i][1] = fmaf(zv, w.y, acc[i][1]);
                    acc[i][2] = fmaf(zv, w.z, acc[i][2]);
                    acc[i][3] = fmaf(zv, w.w, acc[i][3]);
                }
            }
        }
        const float4 b1v = *(const float4*)(b1 + c);
        const float4 g1v = *(const float4*)(g1 + c);
        const float4 s1v = *(const float4*)(bb1 + c);
#pragma unroll
        for (int i = 0; i < 8; i++) {
            float4 uv;
            uv.x = fmaxf(fmaf(g1v.x * (acc[i][0] + b1v.x), kBnInv, s1v.x), 0.0f);
            uv.y = fmaxf(fmaf(g1v.y * (acc[i][1] + b1v.y), kBnInv, s1v.y), 0.0f);
            uv.z = fmaxf(fmaf(g1v.z * (acc[i][2] + b1v.z), kBnInv, s1v.z), 0.0f);
            uv.w = fmaxf(fmaf(g1v.w * (acc[i][3] + b1v.w), kBnInv, s1v.w), 0.0f);
            *(float4*)&us[r0 + i][c] = uv;
        }
    }
    __syncthreads();

    {
        const int c  = (t & 31) * 4;
        const int r0 = (t >> 5) * 4;
        float acc[4][4] = {};
        for (int k4 = 0; k4 < 2 * DD; k4 += 4) {
            float4 ur[4];
#pragma unroll
            for (int i = 0; i < 4; i++) ur[i] = *(const float4*)&us[r0 + i][k4];
#pragma unroll
            for (int kk = 0; kk < 4; kk++) {
                const float4 w = *(const float4*)(W2 + (k4 + kk) * DD + c);
#pragma unroll
                for (int i = 0; i < 4; i++) {
                    const float uv = ((const float*)&ur[i])[kk];
                    acc[i][0] = fmaf(uv, w.x, acc[i][0]);
                    acc[i][1] = fmaf(uv, w.y, acc[i][1]);
                    acc[i][2] = fmaf(uv, w.z, acc[i][2]);
                    acc[i][3] = fmaf(uv, w.w, acc[i][3]);
                }
            }
        }
        const float4 b2v = *(const float4*)(b2 + c);
        const float4 g2v = *(const float4*)(g2 + c);
        const float4 s2v = *(const float4*)(bb2 + c);
#pragma unroll
        for (int i = 0; i < 4; i++) {
            float4 ov;
            ov.x = fmaf(g2v.x * (acc[i][0] + b2v.x), kBnInv, s2v.x);
            ov.y = fmaf(g2v.y * (acc[i][1] + b2v.y), kBnInv, s2v.y);
            ov.z = fmaf(g2v.z * (acc[i][2] + b2v.z), kBnInv, s2v.z);
            ov.w = fmaf(g2v.w * (acc[i][3] + b2v.w), kBnInv, s2v.w);
            if (do_relu) {
                ov.x = fmaxf(ov.x, 0.0f); ov.y = fmaxf(ov.y, 0.0f);
                ov.z = fmaxf(ov.z, 0.0f); ov.w = fmaxf(ov.w, 0.0f);
            }
            *(float4*)(out + (rowbase + r0 + i) * DD + c) = ov;
        }
    }
}

// ---------------------------------------------------------------------------
extern "C" void kernel_launch(void* const* d_in, const int* in_sizes, int n_in,
                              void* d_out, int out_size, void* d_ws, size_t ws_size,
                              hipStream_t stream)
{
    const float* x         = (const float*)d_in[0];
    const float* edge_attr = (const float*)d_in[1];
    const float* node_W    = (const float*)d_in[2];
    const float* node_b    = (const float*)d_in[3];
    const float* edge_W    = (const float*)d_in[4];
    const float* edge_b    = (const float*)d_in[5];
    const float* attn_W    = (const float*)d_in[6];
    const float* attn_b    = (const float*)d_in[7];
    const float* eps       = (const float*)d_in[8];
    const float* W1        = (const float*)d_in[9];
    const float* b1        = (const float*)d_in[10];
    const float* bn1_g     = (const float*)d_in[11];
    const float* bn1_b     = (const float*)d_in[12];
    const float* W2        = (const float*)d_in[13];
    const float* b2        = (const float*)d_in[14];
    const float* bn_g      = (const float*)d_in[15];
    const float* bn_b      = (const float*)d_in[16];
    const int*   edge_index= (const int*)d_in[17];

    float* h    = (float*)d_ws;                     // [N*D]
    float* z    = h + (size_t)NN * DD;              // [N*D]
    float* pi   = z + (size_t)NN * DD;              // [N]
    float* pj   = pi + NN;                          // [N]
    float* a_p  = pj + NN;                          // [E]
    float* ea_p = a_p + EE;                         // [E*16]
    int* counts  = (int*)(ea_p + (size_t)EE * EDD); // [N]
    int* offsets = counts + NN;                     // [N]
    int* cursor  = offsets + NN;                    // [N]
    int* scanned = cursor + NN;                     // [40960]
    int* partials= scanned + 40960;                 // [64]
    int* perm    = partials + 64;                   // [E]
    int* src_p   = perm + EE;                       // [E]
    int* dst_p   = src_p + EE;                      // [E]
    float* out = (float*)d_out;

    node_enc_kernel<<<NN / 32, 256, 0, stream>>>(x, node_W, node_b, h);

    hipMemsetAsync(counts, 0, NN * sizeof(int), stream);
    hist_kernel<<<EE / 256, 256, 0, stream>>>(edge_index, counts);
    scan1_kernel<<<40, 256, 0, stream>>>(counts, scanned, partials);
    scan2_kernel<<<1, 64, 0, stream>>>(partials);
    scan3_kernel<<<(NN + 255) / 256, 256, 0, stream>>>(scanned, partials, offsets, cursor);
    scatter_kernel<<<EE / 256, 256, 0, stream>>>(edge_index, cursor, perm, src_p, dst_p);
    ea_perm_kernel<<<EE / 256, 256, 0, stream>>>(edge_attr, perm, ea_p);

    for (int l = 0; l < LL; l++) {
        attn_pre_kernel<<<NN / 4, 256, 0, stream>>>(
            h, attn_W + (size_t)l * 2 * DD, eps + l, pi, pj, z);
        attn_edge_kernel<<<EE / 256, 256, 0, stream>>>(
            pi, pj, src_p, dst_p, attn_b + l, a_p);
        edge_msg_kernel<<<EE / (4 * CH), 256, 0, stream>>>(
            h, ea_p, a_p, src_p, dst_p,
            edge_W + (size_t)l * EDD * DD, edge_b + (size_t)l * DD, z);
        mlp_kernel<<<NN / 32, 256, 0, stream>>>(
            z,
            W1 + (size_t)l * DD * 2 * DD, b1 + (size_t)l * 2 * DD,
            bn1_g + (size_t)l * 2 * DD, bn1_b + (size_t)l * 2 * DD,
            W2 + (size_t)l * 2 * DD * DD, b2 + (size_t)l * DD,
            bn_g + (size_t)l * DD, bn_b + (size_t)l * DD,
            (l == LL - 1) ? out : h, (l < LL - 1) ? 1 : 0);
    }
}

// Round 6
// 851.865 us; speedup vs baseline: 1.2636x; 1.0041x over previous
//
#include <hip/hip_runtime.h>
#include <math.h>

#define NN 40000
#define EE 640000
#define DD 128
#define EDD 16
#define LL 3
#define CH 32   // edges per wave in edge_msg_kernel

__device__ __constant__ float kBnInv = 0.9999950000374997f; // 1/sqrt(1+1e-5)

// pack two floats to bf16 pair (RTNE) in one uint: lo16=a, hi16=b
__device__ __forceinline__ unsigned pack_bf2(float a, float b) {
    unsigned ua = __float_as_uint(a), ub = __float_as_uint(b);
    ua = (ua + 0x7fffu + ((ua >> 16) & 1u)) >> 16;
    ub = (ub + 0x7fffu + ((ub >> 16) & 1u)) & 0xffff0000u;
    return ua | ub;
}

// ---------------------------------------------------------------------------
// h = x @ node_W + node_b   ([40000,128] @ [128,128]); also emits bf16 hb
__global__ __launch_bounds__(256) void node_enc_kernel(
    const float* __restrict__ x, const float* __restrict__ W,
    const float* __restrict__ b, float* __restrict__ h,
    unsigned* __restrict__ hb)
{
    __shared__ float xs[32][DD];
    const int t = threadIdx.x;
    const long rowbase = (long)blockIdx.x * 32;

    const float4* x4 = (const float4*)(x + rowbase * DD);
    float4* xs4 = (float4*)&xs[0][0];
#pragma unroll
    for (int i = 0; i < 4; i++) xs4[t + i * 256] = x4[t + i * 256];
    __syncthreads();

    const int c  = (t & 31) * 4;
    const int r0 = (t >> 5) * 4;

    float acc[4][4] = {};
    for (int k4 = 0; k4 < DD; k4 += 4) {
        float4 xr[4];
#pragma unroll
        for (int i = 0; i < 4; i++) xr[i] = *(const float4*)&xs[r0 + i][k4];
#pragma unroll
        for (int kk = 0; kk < 4; kk++) {
            const float4 w = *(const float4*)(W + (k4 + kk) * DD + c);
#pragma unroll
            for (int i = 0; i < 4; i++) {
                const float xv = ((const float*)&xr[i])[kk];
                acc[i][0] = fmaf(xv, w.x, acc[i][0]);
                acc[i][1] = fmaf(xv, w.y, acc[i][1]);
                acc[i][2] = fmaf(xv, w.z, acc[i][2]);
                acc[i][3] = fmaf(xv, w.w, acc[i][3]);
            }
        }
    }
    const float4 bv = *(const float4*)(b + c);
#pragma unroll
    for (int i = 0; i < 4; i++) {
        const long row = rowbase + r0 + i;
        float4 ov = { acc[i][0] + bv.x, acc[i][1] + bv.y,
                      acc[i][2] + bv.z, acc[i][3] + bv.w };
        *(float4*)(h + row * DD + c) = ov;
        uint2 pv = { pack_bf2(ov.x, ov.y), pack_bf2(ov.z, ov.w) };
        *(uint2*)(hb + row * 64 + (c >> 1)) = pv;
    }
}

// ---------------------------------------------------------------------------
// CSR build
__global__ __launch_bounds__(256) void hist_kernel(
    const int* __restrict__ edge_index, int* __restrict__ counts)
{
    const int i = blockIdx.x * 256 + threadIdx.x;
    atomicAdd(&counts[edge_index[EE + i]], 1);
}

__global__ __launch_bounds__(256) void scan1_kernel(
    const int* __restrict__ counts, int* __restrict__ scanned,
    int* __restrict__ partials)
{
    __shared__ int sdata[256];
    const int t = threadIdx.x;
    const int base = blockIdx.x * 1024 + t * 4;
    int v[4]; int sum = 0;
#pragma unroll
    for (int i = 0; i < 4; i++) {
        const int idx = base + i;
        v[i] = (idx < NN) ? counts[idx] : 0;
        sum += v[i];
    }
    sdata[t] = sum;
    __syncthreads();
    for (int off = 1; off < 256; off <<= 1) {
        int x = (t >= off) ? sdata[t - off] : 0;
        __syncthreads();
        sdata[t] += x;
        __syncthreads();
    }
    int run = sdata[t] - sum;
#pragma unroll
    for (int i = 0; i < 4; i++) {
        const int idx = base + i;
        if (idx < NN) scanned[idx] = run;
        run += v[i];
    }
    if (t == 255) partials[blockIdx.x] = sdata[255];
}

__global__ void scan2_kernel(int* __restrict__ partials)
{
    if (threadIdx.x == 0) {
        int run = 0;
        for (int i = 0; i < 40; i++) { int v = partials[i]; partials[i] = run; run += v; }
    }
}

__global__ __launch_bounds__(256) void scan3_kernel(
    const int* __restrict__ scanned, const int* __restrict__ partials,
    int* __restrict__ offsets, int* __restrict__ cursor)
{
    const int idx = blockIdx.x * 256 + threadIdx.x;
    if (idx < NN) {
        const int off = scanned[idx] + partials[idx >> 10];
        offsets[idx] = off;
        cursor[idx]  = off;
    }
}

__global__ __launch_bounds__(256) void scatter_kernel(
    const int* __restrict__ edge_index, int* __restrict__ cursor,
    int* __restrict__ perm, int* __restrict__ src_p, int* __restrict__ dst_p)
{
    const int i = blockIdx.x * 256 + threadIdx.x;
    const int src = edge_index[i];
    const int dst = edge_index[EE + i];
    const int pos = atomicAdd(&cursor[dst], 1);
    perm[pos] = i;
    src_p[pos] = src;
    dst_p[pos] = dst;
}

__global__ __launch_bounds__(256) void ea_perm_kernel(
    const float* __restrict__ edge_attr, const int* __restrict__ perm,
    float* __restrict__ ea_p)
{
    const int pos = blockIdx.x * 256 + threadIdx.x;
    const int e = perm[pos];
    const float4* sp = (const float4*)(edge_attr + (long)e * EDD);
    float4* dp = (float4*)(ea_p + (long)pos * EDD);
    dp[0] = sp[0]; dp[1] = sp[1]; dp[2] = sp[2]; dp[3] = sp[3];
}

// ---------------------------------------------------------------------------
// per-node attention partials + z init (z = (1+eps)*h); fp32 h for precision
__global__ __launch_bounds__(256) void attn_pre_kernel(
    const float* __restrict__ h, const float* __restrict__ aW,
    const float* __restrict__ eps_p,
    float* __restrict__ pi, float* __restrict__ pj, float* __restrict__ z)
{
    const int wid  = threadIdx.x >> 6;
    const int lane = threadIdx.x & 63;
    const int n = blockIdx.x * 4 + wid;
    const int c0 = lane, c1 = lane + 64;
    const float ep = 1.0f + eps_p[0];
    const float h0 = h[(long)n * DD + c0], h1 = h[(long)n * DD + c1];

    z[(long)n * DD + c0] = ep * h0;
    z[(long)n * DD + c1] = ep * h1;

    float a = h0 * aW[c0]      + h1 * aW[c1];
    float b = h0 * aW[DD + c0] + h1 * aW[DD + c1];
#pragma unroll
    for (int off = 32; off > 0; off >>= 1) {
        a += __shfl_xor(a, off, 64);
        b += __shfl_xor(b, off, 64);
    }
    if (lane == 0) { pi[n] = a; pj[n] = b; }
}

// per-edge attention coefficient in CSR order
__global__ __launch_bounds__(256) void attn_edge_kernel(
    const float* __restrict__ pi, const float* __restrict__ pj,
    const int* __restrict__ src_p, const int* __restrict__ dst_p,
    const float* __restrict__ ab_p, float* __restrict__ a_p)
{
    const int idx = blockIdx.x * 256 + threadIdx.x;
    const float s = pi[dst_p[idx]] + pj[src_p[idx]] + ab_p[0];
    a_p[idx] = 1.0f / (1.0f + expf(-s));
}

// ---------------------------------------------------------------------------
// Edge-parallel segmented aggregation, batch-4 load-hoisted.
// Lane owns cols (2*lane, 2*lane+1); h gathered as one packed-bf16 dword.
// z must be pre-initialized to (1+eps)*h.
__global__ __launch_bounds__(256) void edge_msg_kernel(
    const unsigned* __restrict__ hb, const float* __restrict__ ea_p,
    const float* __restrict__ a_p,
    const int* __restrict__ src_p, const int* __restrict__ dst_p,
    const float* __restrict__ eW, const float* __restrict__ eb,
    float* __restrict__ z)
{
    const int wid  = threadIdx.x >> 6;
    const int lane = threadIdx.x & 63;
    const long e0  = ((long)blockIdx.x * 4 + wid) * CH;  // grid = EE/(4*CH)
    const int c0 = lane * 2, c1 = c0 + 1;

    float ew0[EDD], ew1[EDD];
#pragma unroll
    for (int q = 0; q < EDD; q++) {
        const float2 w2 = ((const float2*)(eW + q * DD))[lane];
        ew0[q] = w2.x; ew1[q] = w2.y;
    }
    const float2 eb2 = ((const float2*)eb)[lane];
    const float eb0 = eb2.x, eb1 = eb2.y;

    float acc0 = 0.0f, acc1 = 0.0f;
    int cur = dst_p[e0];

    for (int k4 = 0; k4 < CH; k4 += 4) {
        const long e = e0 + k4;

        // ---- load phase (branch-free; streams + gathers for 4 edges) ----
        int dsts[4], srcs[4];
        float av[4];
#pragma unroll
        for (int j = 0; j < 4; j++) {
            dsts[j] = dst_p[e + j];
            srcs[j] = src_p[e + j];
            av[j]   = a_p[e + j];
        }
        float xj0[4], xj1[4];
#pragma unroll
        for (int j = 0; j < 4; j++) {
            const unsigned u = hb[(long)srcs[j] * 64 + lane];
            xj0[j] = __uint_as_float(u << 16);
            xj1[j] = __uint_as_float(u & 0xffff0000u);
        }
        float ev0[4], ev1[4];
#pragma unroll
        for (int j = 0; j < 4; j++) {
            const float4* eap = (const float4*)(ea_p + (e + j) * EDD);
            const float4 t0 = eap[0], t1 = eap[1], t2 = eap[2], t3 = eap[3];
            float s0 = eb0, s1 = eb1;
            s0 = fmaf(t0.x, ew0[0],  s0); s1 = fmaf(t0.x, ew1[0],  s1);
            s0 = fmaf(t0.y, ew0[1],  s0); s1 = fmaf(t0.y, ew1[1],  s1);
            s0 = fmaf(t0.z, ew0[2],  s0); s1 = fmaf(t0.z, ew1[2],  s1);
            s0 = fmaf(t0.w, ew0[3],  s0); s1 = fmaf(t0.w, ew1[3],  s1);
            s0 = fmaf(t1.x, ew0[4],  s0); s1 = fmaf(t1.x, ew1[4],  s1);
            s0 = fmaf(t1.y, ew0[5],  s0); s1 = fmaf(t1.y, ew1[5],  s1);
            s0 = fmaf(t1.z, ew0[6],  s0); s1 = fmaf(t1.z, ew1[6],  s1);
            s0 = fmaf(t1.w, ew0[7],  s0); s1 = fmaf(t1.w, ew1[7],  s1);
            s0 = fmaf(t2.x, ew0[8],  s0); s1 = fmaf(t2.x, ew1[8],  s1);
            s0 = fmaf(t2.y, ew0[9],  s0); s1 = fmaf(t2.y, ew1[9],  s1);
            s0 = fmaf(t2.z, ew0[10], s0); s1 = fmaf(t2.z, ew1[10], s1);
            s0 = fmaf(t2.w, ew0[11], s0); s1 = fmaf(t2.w, ew1[11], s1);
            s0 = fmaf(t3.x, ew0[12], s0); s1 = fmaf(t3.x, ew1[12], s1);
            s0 = fmaf(t3.y, ew0[13], s0); s1 = fmaf(t3.y, ew1[13], s1);
            s0 = fmaf(t3.z, ew0[14], s0); s1 = fmaf(t3.z, ew1[14], s1);
            s0 = fmaf(t3.w, ew0[15], s0); s1 = fmaf(t3.w, ew1[15], s1);
            ev0[j] = s0; ev1[j] = s1;
        }

        // ---- consume phase (wave-uniform branch, registers only) ----
#pragma unroll
        for (int j = 0; j < 4; j++) {
            if (dsts[j] != cur) {
                atomicAdd(&z[(long)cur * DD + c0], acc0);
                atomicAdd(&z[(long)cur * DD + c1], acc1);
                acc0 = 0.0f; acc1 = 0.0f;
                cur = dsts[j];
            }
            acc0 += fmaxf(fmaf(xj0[j], av[j], ev0[j]), 0.0f);
            acc1 += fmaxf(fmaf(xj1[j], av[j], ev1[j]), 0.0f);
        }
    }
    atomicAdd(&z[(long)cur * DD + c0], acc0);
    atomicAdd(&z[(long)cur * DD + c1], acc1);
}

// ---------------------------------------------------------------------------
// Fused GIN MLP, 32 rows/block; also emits bf16 hb for the next layer's gather
__global__ __launch_bounds__(256) void mlp_kernel(
    const float* __restrict__ zin,
    const float* __restrict__ W1, const float* __restrict__ b1,
    const float* __restrict__ g1, const float* __restrict__ bb1,
    const float* __restrict__ W2, const float* __restrict__ b2,
    const float* __restrict__ g2, const float* __restrict__ bb2,
    float* __restrict__ out, unsigned* __restrict__ hb, const int do_relu)
{
    __shared__ float zs[32][DD];
    __shared__ float us[32][2 * DD];
    const int t = threadIdx.x;
    const long rowbase = (long)blockIdx.x * 32;

    const float4* z4in = (const float4*)(zin + rowbase * DD);
    float4* z4 = (float4*)&zs[0][0];
#pragma unroll
    for (int i = 0; i < 4; i++) z4[t + i * 256] = z4in[t + i * 256];
    __syncthreads();

    {
        const int c  = (t & 63) * 4;
        const int r0 = (t >> 6) * 8;
        float acc[8][4] = {};
        for (int k4 = 0; k4 < DD; k4 += 4) {
            float4 zr[8];
#pragma unroll
            for (int i = 0; i < 8; i++) zr[i] = *(const float4*)&zs[r0 + i][k4];
#pragma unroll
            for (int kk = 0; kk < 4; kk++) {
                const float4 w = *(const float4*)(W1 + (k4 + kk) * 2 * DD + c);
#pragma unroll
                for (int i = 0; i < 8; i++) {
                    const float zv = ((const float*)&zr[i])[kk];
                    acc[i][0] = fmaf(zv, w.x, acc[i][0]);
                    acc[i][1] = fmaf(zv, w.y, acc[i][1]);
                    acc[i][2] = fmaf(zv, w.z, acc[i][2]);
                    acc[i][3] = fmaf(zv, w.w, acc[i][3]);
                }
            }
        }
        const float4 b1v = *(const float4*)(b1 + c);
        const float4 g1v = *(const float4*)(g1 + c);
        const float4 s1v = *(const float4*)(bb1 + c);
#pragma unroll
        for (int i = 0; i < 8; i++) {
            float4 uv;
            uv.x = fmaxf(fmaf(g1v.x * (acc[i][0] + b1v.x), kBnInv, s1v.x), 0.0f);
            uv.y = fmaxf(fmaf(g1v.y * (acc[i][1] + b1v.y), kBnInv, s1v.y), 0.0f);
            uv.z = fmaxf(fmaf(g1v.z * (acc[i][2] + b1v.z), kBnInv, s1v.z), 0.0f);
            uv.w = fmaxf(fmaf(g1v.w * (acc[i][3] + b1v.w), kBnInv, s1v.w), 0.0f);
            *(float4*)&us[r0 + i][c] = uv;
        }
    }
    __syncthreads();

    {
        const int c  = (t & 31) * 4;
        const int r0 = (t >> 5) * 4;
        float acc[4][4] = {};
        for (int k4 = 0; k4 < 2 * DD; k4 += 4) {
            float4 ur[4];
#pragma unroll
            for (int i = 0; i < 4; i++) ur[i] = *(const float4*)&us[r0 + i][k4];
#pragma unroll
            for (int kk = 0; kk < 4; kk++) {
                const float4 w = *(const float4*)(W2 + (k4 + kk) * DD + c);
#pragma unroll
                for (int i = 0; i < 4; i++) {
                    const float uv = ((const float*)&ur[i])[kk];
                    acc[i][0] = fmaf(uv, w.x, acc[i][0]);
                    acc[i][1] = fmaf(uv, w.y, acc[i][1]);
                    acc[i][2] = fmaf(uv, w.z, acc[i][2]);
                    acc[i][3] = fmaf(uv, w.w, acc[i][3]);
                }
            }
        }
        const float4 b2v = *(const float4*)(b2 + c);
        const float4 g2v = *(const float4*)(g2 + c);
        const float4 s2v = *(const float4*)(bb2 + c);
#pragma unroll
        for (int i = 0; i < 4; i++) {
            const long row = rowbase + r0 + i;
            float4 ov;
            ov.x = fmaf(g2v.x * (acc[i][0] + b2v.x), kBnInv, s2v.x);
            ov.y = fmaf(g2v.y * (acc[i][1] + b2v.y), kBnInv, s2v.y);
            ov.z = fmaf(g2v.z * (acc[i][2] + b2v.z), kBnInv, s2v.z);
            ov.w = fmaf(g2v.w * (acc[i][3] + b2v.w), kBnInv, s2v.w);
            if (do_relu) {
                ov.x = fmaxf(ov.x, 0.0f); ov.y = fmaxf(ov.y, 0.0f);
                ov.z = fmaxf(ov.z, 0.0f); ov.w = fmaxf(ov.w, 0.0f);
            }
            *(float4*)(out + row * DD + c) = ov;
            uint2 pv = { pack_bf2(ov.x, ov.y), pack_bf2(ov.z, ov.w) };
            *(uint2*)(hb + row * 64 + (c >> 1)) = pv;
        }
    }
}

// ---------------------------------------------------------------------------
extern "C" void kernel_launch(void* const* d_in, const int* in_sizes, int n_in,
                              void* d_out, int out_size, void* d_ws, size_t ws_size,
                              hipStream_t stream)
{
    const float* x         = (const float*)d_in[0];
    const float* edge_attr = (const float*)d_in[1];
    const float* node_W    = (const float*)d_in[2];
    const float* node_b    = (const float*)d_in[3];
    const float* edge_W    = (const float*)d_in[4];
    const float* edge_b    = (const float*)d_in[5];
    const float* attn_W    = (const float*)d_in[6];
    const float* attn_b    = (const float*)d_in[7];
    const float* eps       = (const float*)d_in[8];
    const float* W1        = (const float*)d_in[9];
    const float* b1        = (const float*)d_in[10];
    const float* bn1_g     = (const float*)d_in[11];
    const float* bn1_b     = (const float*)d_in[12];
    const float* W2        = (const float*)d_in[13];
    const float* b2        = (const float*)d_in[14];
    const float* bn_g      = (const float*)d_in[15];
    const float* bn_b      = (const float*)d_in[16];
    const int*   edge_index= (const int*)d_in[17];

    float* h    = (float*)d_ws;                     // [N*D]
    float* z    = h + (size_t)NN * DD;              // [N*D]
    float* pi   = z + (size_t)NN * DD;              // [N]
    float* pj   = pi + NN;                          // [N]
    float* a_p  = pj + NN;                          // [E]
    float* ea_p = a_p + EE;                         // [E*16]
    unsigned* hbuf = (unsigned*)(ea_p + (size_t)EE * EDD); // [N*64] packed bf16
    int* counts  = (int*)(hbuf + (size_t)NN * 64);  // [N]
    int* offsets = counts + NN;                     // [N]
    int* cursor  = offsets + NN;                    // [N]
    int* scanned = cursor + NN;                     // [40960]
    int* partials= scanned + 40960;                 // [64]
    int* perm    = partials + 64;                   // [E]
    int* src_p   = perm + EE;                       // [E]
    int* dst_p   = src_p + EE;                      // [E]
    float* out = (float*)d_out;

    node_enc_kernel<<<NN / 32, 256, 0, stream>>>(x, node_W, node_b, h, hbuf);

    hipMemsetAsync(counts, 0, NN * sizeof(int), stream);
    hist_kernel<<<EE / 256, 256, 0, stream>>>(edge_index, counts);
    scan1_kernel<<<40, 256, 0, stream>>>(counts, scanned, partials);
    scan2_kernel<<<1, 64, 0, stream>>>(partials);
    scan3_kernel<<<(NN + 255) / 256, 256, 0, stream>>>(scanned, partials, offsets, cursor);
    scatter_kernel<<<EE / 256, 256, 0, stream>>>(edge_index, cursor, perm, src_p, dst_p);
    ea_perm_kernel<<<EE / 256, 256, 0, stream>>>(edge_attr, perm, ea_p);

    for (int l = 0; l < LL; l++) {
        attn_pre_kernel<<<NN / 4, 256, 0, stream>>>(
            h, attn_W + (size_t)l * 2 * DD, eps + l, pi, pj, z);
        attn_edge_kernel<<<EE / 256, 256, 0, stream>>>(
            pi, pj, src_p, dst_p, attn_b + l, a_p);
        edge_msg_kernel<<<EE / (4 * CH), 256, 0, stream>>>(
            hbuf, ea_p, a_p, src_p, dst_p,
            edge_W + (size_t)l * EDD * DD, edge_b + (size_t)l * DD, z);
        mlp_kernel<<<NN / 32, 256, 0, stream>>>(
            z,
            W1 + (size_t)l * DD * 2 * DD, b1 + (size_t)l * 2 * DD,
            bn1_g + (size_t)l * 2 * DD, bn1_b + (size_t)l * 2 * DD,
            W2 + (size_t)l * 2 * DD * DD, b2 + (size_t)l * DD,
            bn_g + (size_t)l * DD, bn_b + (size_t)l * DD,
            (l == LL - 1) ? out : h, hbuf, (l < LL - 1) ? 1 : 0);
    }
}